// Round 3
// baseline (4240.983 us; speedup 1.0000x reference)
//
#include <hip/hip_runtime.h>

#define H       64
#define NSLOT   4
#define NSTEP   23          // SEQ_LEN - 1
#define NB      65536
#define NV      66          // VOCAB_SIZE + 2
#define SEQL    24
#define EPB     64          // elements per 256-thread block (4 lanes/element)
#define LSTRIDE 65          // act leading stride: conflict-free reads, 2-way writes

// ---- workspace layout (float offsets) ----
#define OFF_EW1   0                         // embW1b  [NV][H] = embed@W1[:64] + b1
#define OFF_EWR1  (NV * H)                  // embWr1b [NV][H] = embed@Wr1[:64] + br1

__global__ __launch_bounds__(256) void k_setup_tables(
    const float* __restrict__ embed, const float* __restrict__ W1, const float* __restrict__ b1,
    const float* __restrict__ Wr1, const float* __restrict__ br1, float* __restrict__ ws)
{
    int idx = blockIdx.x * 256 + threadIdx.x;
    if (idx >= NV * H) return;
    int t = idx >> 6, k = idx & 63;
    float a1 = b1[k], a2 = br1[k];
    for (int j = 0; j < H; ++j) {
        float e = embed[t * H + j];
        a1 = fmaf(e, W1[j * H + k], a1);
        a2 = fmaf(e, Wr1[j * H + k], a2);
    }
    ws[OFF_EW1 + idx]  = a1;
    ws[OFF_EWR1 + idx] = a2;
}

// 16-wide FMA into ACC from weight row chunk (per-lane VMEM, vmcnt path)
#define FMA16(a, wptr, ACC) do {                                            \
    const float4* _w = (const float4*)(wptr);                               \
    float4 _w0 = _w[0], _w1 = _w[1], _w2 = _w[2], _w3 = _w[3];              \
    ACC[ 0]=fmaf((a),_w0.x,ACC[ 0]); ACC[ 1]=fmaf((a),_w0.y,ACC[ 1]);      \
    ACC[ 2]=fmaf((a),_w0.z,ACC[ 2]); ACC[ 3]=fmaf((a),_w0.w,ACC[ 3]);      \
    ACC[ 4]=fmaf((a),_w1.x,ACC[ 4]); ACC[ 5]=fmaf((a),_w1.y,ACC[ 5]);      \
    ACC[ 6]=fmaf((a),_w1.z,ACC[ 6]); ACC[ 7]=fmaf((a),_w1.w,ACC[ 7]);      \
    ACC[ 8]=fmaf((a),_w2.x,ACC[ 8]); ACC[ 9]=fmaf((a),_w2.y,ACC[ 9]);      \
    ACC[10]=fmaf((a),_w2.z,ACC[10]); ACC[11]=fmaf((a),_w2.w,ACC[11]);      \
    ACC[12]=fmaf((a),_w3.x,ACC[12]); ACC[13]=fmaf((a),_w3.y,ACC[13]);      \
    ACC[14]=fmaf((a),_w3.z,ACC[14]); ACC[15]=fmaf((a),_w3.w,ACC[15]);      \
} while (0)

#define LOAD16(ptr, ACC) do {                                               \
    const float4* _b = (const float4*)(ptr);                                \
    float4 _b0 = _b[0], _b1 = _b[1], _b2 = _b[2], _b3 = _b[3];              \
    ACC[ 0]=_b0.x; ACC[ 1]=_b0.y; ACC[ 2]=_b0.z; ACC[ 3]=_b0.w;            \
    ACC[ 4]=_b1.x; ACC[ 5]=_b1.y; ACC[ 6]=_b1.z; ACC[ 7]=_b1.w;            \
    ACC[ 8]=_b2.x; ACC[ 9]=_b2.y; ACC[10]=_b2.z; ACC[11]=_b2.w;            \
    ACC[12]=_b3.x; ACC[13]=_b3.y; ACC[14]=_b3.z; ACC[15]=_b3.w;            \
} while (0)

__global__ __launch_bounds__(256, 4) void k_main(
    const float* __restrict__ W1, const float* __restrict__ W2, const float* __restrict__ b2,
    const float* __restrict__ Ww, const float* __restrict__ bw,
    const float* __restrict__ We, const float* __restrict__ be,
    const float* __restrict__ Wr1, const float* __restrict__ Wr2, const float* __restrict__ br2,
    const int* __restrict__ qtok, const int* __restrict__ seqs,
    const float* __restrict__ ws, float* __restrict__ out)
{
    // act[k*65 + elem]: per-element activation column shared by its 4 lanes.
    // Same-wave LDS is in-order -> no __syncthreads needed anywhere.
    __shared__ float act[H * LSTRIDE];
    const int tid  = threadIdx.x;
    const int m    = tid & 3;          // output-chunk id (16 floats) & evict-slot id
    const int elem = tid >> 2;         // 0..63 within block
    const int eb   = blockIdx.x * EPB + elem;
    const int k0   = m * 16;

    const float* embW1b  = ws + OFF_EW1;
    const float* embWr1b = ws + OFF_EWR1;

    // memory state lives in registers: 4 slots x 16 floats per lane
    float mem0[16], mem1[16], mem2[16], mem3[16], contrib[16];
#pragma unroll
    for (int i = 0; i < 16; ++i) {
        mem0[i] = 0.f; mem1[i] = 0.f; mem2[i] = 0.f; mem3[i] = 0.f; contrib[i] = 0.f;
    }

    const float bem = be[m];
    int tok = seqs[eb * SEQL];

    float acc[16];

#pragma unroll 1
    for (int t = 0; t < NSTEP; ++t) {
        int tok_n = seqs[eb * SEQL + t + 1];   // t+1 <= 23 < SEQL: always in-bounds

        // h1 = relu(embW1b[tok] + contrib) -> act
        {
            float h[16];
            LOAD16(embW1b + tok * H + k0, h);
#pragma unroll
            for (int i = 0; i < 16; ++i)
                act[(k0 + i) * LSTRIDE + elem] = fmaxf(h[i] + contrib[i], 0.f);
        }

        // h2 = relu(h1 @ W2 + b2)
        LOAD16(b2 + k0, acc);
#pragma unroll 2
        for (int j = 0; j < H; ++j) {
            float a = act[j * LSTRIDE + elem];
            FMA16(a, W2 + j * H + k0, acc);
        }
#pragma unroll
        for (int i = 0; i < 16; ++i)
            act[(k0 + i) * LSTRIDE + elem] = fmaxf(acc[i], 0.f);

        // write_vec = h2 @ Ww + bw (chunk); evict logit for slot m
        float lg = bem;
        LOAD16(bw + k0, acc);
#pragma unroll 2
        for (int j = 0; j < H; ++j) {
            float a = act[j * LSTRIDE + elem];
            FMA16(a, Ww + j * H + k0, acc);
            lg = fmaf(a, We[j * NSLOT + m], lg);
        }

        // gather the element's 4 logits via in-wave butterfly (lanes 4e..4e+3)
        float la = lg;
        float lb = __shfl_xor(la, 1);
        float lc = __shfl_xor(la, 2);
        float ld = __shfl_xor(lb, 2);
        // slot-ordered values (slot of la is m, lb is m^1, lc is m^2, ld is m^3)
        float v0 = (m == 0) ? la : (m == 1) ? lb : (m == 2) ? lc : ld;
        float v1 = (m == 1) ? la : (m == 0) ? lb : (m == 3) ? lc : ld;
        float v2 = (m == 2) ? la : (m == 3) ? lb : (m == 0) ? lc : ld;
        float v3 = (m == 3) ? la : (m == 2) ? lb : (m == 1) ? lc : ld;
        int e = 0; float best = v0;                 // first-max wins = jnp.argmax
        if (v1 > best) { best = v1; e = 1; }
        if (v2 > best) { best = v2; e = 2; }
        if (v3 > best) { best = v3; e = 3; }

        // mem[e] <- write_vec ; delta = write_vec - mem_old[e] -> act
#pragma unroll
        for (int i = 0; i < 16; ++i) {
            float old = (e == 0) ? mem0[i] : (e == 1) ? mem1[i] : (e == 2) ? mem2[i] : mem3[i];
            float w = acc[i];
            mem0[i] = (e == 0) ? w : mem0[i];
            mem1[i] = (e == 1) ? w : mem1[i];
            mem2[i] = (e == 2) ? w : mem2[i];
            mem3[i] = (e == 3) ? w : mem3[i];
            act[(k0 + i) * LSTRIDE + elem] = w - old;
        }

        // contrib += delta @ W1mem_e  (single slot; e uniform across the element's lanes)
        const float* W1e = W1 + (H + e * H) * H + k0;
#pragma unroll 2
        for (int j = 0; j < H; ++j) {
            float d = act[j * LSTRIDE + elem];
            FMA16(d, W1e + j * H, contrib);
        }

        tok = tok_n;
    }

    // ---- read head ----
#pragma unroll
    for (int i = 0; i < 16; ++i)
        act[(k0 + i) * LSTRIDE + elem] = 0.25f * (mem0[i] + mem1[i] + mem2[i] + mem3[i]);

    int q = qtok[eb];
    LOAD16(embWr1b + q * H + k0, acc);
#pragma unroll 2
    for (int j = 0; j < H; ++j) {
        float a = act[j * LSTRIDE + elem];
        FMA16(a, Wr1 + (H + j) * H + k0, acc);
    }
#pragma unroll
    for (int i = 0; i < 16; ++i)
        act[(k0 + i) * LSTRIDE + elem] = fmaxf(acc[i], 0.f);

    LOAD16(br2 + k0, acc);
#pragma unroll 2
    for (int j = 0; j < H; ++j) {
        float a = act[j * LSTRIDE + elem];
        FMA16(a, Wr2 + j * H + k0, acc);
    }

    float4* o4 = (float4*)(out + (size_t)eb * H + k0);
    o4[0] = make_float4(acc[ 0], acc[ 1], acc[ 2], acc[ 3]);
    o4[1] = make_float4(acc[ 4], acc[ 5], acc[ 6], acc[ 7]);
    o4[2] = make_float4(acc[ 8], acc[ 9], acc[10], acc[11]);
    o4[3] = make_float4(acc[12], acc[13], acc[14], acc[15]);
}

extern "C" void kernel_launch(void* const* d_in, const int* in_sizes, int n_in,
                              void* d_out, int out_size, void* d_ws, size_t ws_size,
                              hipStream_t stream)
{
    const int*   seqs  = (const int*)d_in[0];
    const int*   qtok  = (const int*)d_in[1];
    const float* embed = (const float*)d_in[2];
    const float* W1    = (const float*)d_in[3];
    const float* b1    = (const float*)d_in[4];
    const float* W2    = (const float*)d_in[5];
    const float* b2    = (const float*)d_in[6];
    const float* Ww    = (const float*)d_in[7];
    const float* bw    = (const float*)d_in[8];
    const float* We    = (const float*)d_in[9];
    const float* be    = (const float*)d_in[10];
    const float* Wr1   = (const float*)d_in[11];
    const float* br1   = (const float*)d_in[12];
    const float* Wr2   = (const float*)d_in[13];
    const float* br2   = (const float*)d_in[14];
    float* out = (float*)d_out;
    float* ws  = (float*)d_ws;

    hipLaunchKernelGGL(k_setup_tables, dim3((NV * H + 255) / 256), dim3(256), 0, stream,
                       embed, W1, b1, Wr1, br1, ws);
    hipLaunchKernelGGL(k_main, dim3(NB / EPB), dim3(256), 0, stream,
                       W1, W2, b2, Ww, bw, We, be, Wr1, Wr2, br2, qtok, seqs, ws, out);
}

// Round 4
// 2175.748 us; speedup vs baseline: 1.9492x; 1.9492x over previous
//
#include <hip/hip_runtime.h>

#define H       64
#define NSLOT   4
#define NSTEP   23          // SEQ_LEN - 1
#define NB      65536
#define NV      66          // VOCAB_SIZE + 2
#define SEQL    24
#define LPE     8           // lanes per element
#define EPB     32          // elements per 256-thread block
#define ASTRIDE 33          // act leading stride (33%32==1: 2-way writes, broadcast reads)

// ---- workspace layout (float offsets) ----
#define OFF_EW1   0                         // embW1b  [NV][H] = embed@W1[:64] + b1
#define OFF_EWR1  (NV * H)                  // embWr1b [NV][H] = embed@Wr1[:64] + br1

__global__ __launch_bounds__(256) void k_setup_tables(
    const float* __restrict__ embed, const float* __restrict__ W1, const float* __restrict__ b1,
    const float* __restrict__ Wr1, const float* __restrict__ br1, float* __restrict__ ws)
{
    int idx = blockIdx.x * 256 + threadIdx.x;
    if (idx >= NV * H) return;
    int t = idx >> 6, k = idx & 63;
    float a1 = b1[k], a2 = br1[k];
    for (int j = 0; j < H; ++j) {
        float e = embed[t * H + j];
        a1 = fmaf(e, W1[j * H + k], a1);
        a2 = fmaf(e, Wr1[j * H + k], a2);
    }
    ws[OFF_EW1 + idx]  = a1;
    ws[OFF_EWR1 + idx] = a2;
}

// 8-wide FMA into ACC from a weight-row chunk (2x global_load_dwordx4, vmcnt path)
#define FMA8(a, wptr, ACC) do {                                             \
    const float4* _w = (const float4*)(wptr);                               \
    float4 _w0 = _w[0], _w1 = _w[1];                                        \
    ACC[0]=fmaf((a),_w0.x,ACC[0]); ACC[1]=fmaf((a),_w0.y,ACC[1]);          \
    ACC[2]=fmaf((a),_w0.z,ACC[2]); ACC[3]=fmaf((a),_w0.w,ACC[3]);          \
    ACC[4]=fmaf((a),_w1.x,ACC[4]); ACC[5]=fmaf((a),_w1.y,ACC[5]);          \
    ACC[6]=fmaf((a),_w1.z,ACC[6]); ACC[7]=fmaf((a),_w1.w,ACC[7]);          \
} while (0)

#define LOAD8(ptr, A) do {                                                  \
    const float4* _b = (const float4*)(ptr);                                \
    float4 _b0 = _b[0], _b1 = _b[1];                                        \
    A[0]=_b0.x; A[1]=_b0.y; A[2]=_b0.z; A[3]=_b0.w;                        \
    A[4]=_b1.x; A[5]=_b1.y; A[6]=_b1.z; A[7]=_b1.w;                        \
} while (0)

__global__ __launch_bounds__(256, 4) void k_main(
    const float* __restrict__ W1, const float* __restrict__ W2, const float* __restrict__ b2,
    const float* __restrict__ Ww, const float* __restrict__ bw,
    const float* __restrict__ We, const float* __restrict__ be,
    const float* __restrict__ Wr1, const float* __restrict__ Wr2, const float* __restrict__ br2,
    const int* __restrict__ qtok, const int* __restrict__ seqs,
    const float* __restrict__ ws, float* __restrict__ out)
{
    // act[k*33 + elem]: per-element activation column. Each element's 8 lanes live
    // in ONE wave (LPE divides 64) -> lockstep program order, no barriers needed.
    // Columns are private per element -> no cross-wave hazard either.
    __shared__ float act[H * ASTRIDE];
    const int tid  = threadIdx.x;
    const int m    = tid & (LPE - 1);      // chunk id 0..7
    const int elem = tid >> 3;             // 0..31 within block
    const int eb   = blockIdx.x * EPB + elem;
    const int k0   = m * 8;
    const int slot = m & 3;                // evict-logit slot this lane computes

    const float* embW1b  = ws + OFF_EW1;
    const float* embWr1b = ws + OFF_EWR1;

    // register-resident memory state: 4 slots x 8 floats per lane (32 VGPRs)
    float mem0[8], mem1[8], mem2[8], mem3[8], contrib[8];
#pragma unroll
    for (int i = 0; i < 8; ++i) {
        mem0[i] = 0.f; mem1[i] = 0.f; mem2[i] = 0.f; mem3[i] = 0.f; contrib[i] = 0.f;
    }

    const float bes = be[slot];
    int tok = seqs[eb * SEQL];

    float acc[8];

#pragma unroll 1
    for (int t = 0; t < NSTEP; ++t) {
        int tok_n = seqs[eb * SEQL + t + 1];   // t+1 <= 23 < SEQL

        // h1 = relu(embW1b[tok] + contrib) -> act
        {
            float h[8];
            LOAD8(embW1b + tok * H + k0, h);
#pragma unroll
            for (int i = 0; i < 8; ++i)
                act[(k0 + i) * ASTRIDE + elem] = fmaxf(h[i] + contrib[i], 0.f);
        }

        // h2 = relu(h1 @ W2 + b2)
        LOAD8(b2 + k0, acc);
#pragma unroll 2
        for (int j = 0; j < H; ++j) {
            float a = act[j * ASTRIDE + elem];
            FMA8(a, W2 + j * H + k0, acc);
        }
#pragma unroll
        for (int i = 0; i < 8; ++i)
            act[(k0 + i) * ASTRIDE + elem] = fmaxf(acc[i], 0.f);

        // write_vec chunk = h2 @ Ww + bw ; evict logit for slot (m&3)
        float lg = bes;
        LOAD8(bw + k0, acc);
#pragma unroll 2
        for (int j = 0; j < H; ++j) {
            float a = act[j * ASTRIDE + elem];
            FMA8(a, Ww + j * H + k0, acc);
            lg = fmaf(a, We[j * NSLOT + slot], lg);
        }

        // gather the element's 4 logits (lanes base..base+3 hold slots 0..3)
        int base = tid & ~(LPE - 1);
        float v0 = __shfl(lg, base + 0);
        float v1 = __shfl(lg, base + 1);
        float v2 = __shfl(lg, base + 2);
        float v3 = __shfl(lg, base + 3);
        int e = 0; float best = v0;                 // first-max wins = jnp.argmax
        if (v1 > best) { best = v1; e = 1; }
        if (v2 > best) { best = v2; e = 2; }
        if (v3 > best) { best = v3; e = 3; }

        // mem[e] <- write_vec ; delta = write_vec - mem_old[e] -> act
        bool e0 = (e == 0), e1 = (e == 1), e2 = (e == 2), e3 = (e == 3);
#pragma unroll
        for (int i = 0; i < 8; ++i) {
            float old = e0 ? mem0[i] : e1 ? mem1[i] : e2 ? mem2[i] : mem3[i];
            float w = acc[i];
            mem0[i] = e0 ? w : mem0[i];
            mem1[i] = e1 ? w : mem1[i];
            mem2[i] = e2 ? w : mem2[i];
            mem3[i] = e3 ? w : mem3[i];
            act[(k0 + i) * ASTRIDE + elem] = w - old;
        }

        // contrib += delta @ W1mem_e (e uniform across the element's lanes)
        const float* W1e = W1 + (H + e * H) * H + k0;
#pragma unroll 2
        for (int j = 0; j < H; ++j) {
            float d = act[j * ASTRIDE + elem];
            FMA8(d, W1e + j * H, contrib);
        }

        tok = tok_n;
    }

    // ---- read head ----
#pragma unroll
    for (int i = 0; i < 8; ++i)
        act[(k0 + i) * ASTRIDE + elem] = 0.25f * (mem0[i] + mem1[i] + mem2[i] + mem3[i]);

    int q = qtok[eb];
    LOAD8(embWr1b + q * H + k0, acc);
#pragma unroll 2
    for (int j = 0; j < H; ++j) {
        float a = act[j * ASTRIDE + elem];
        FMA8(a, Wr1 + (H + j) * H + k0, acc);
    }
#pragma unroll
    for (int i = 0; i < 8; ++i)
        act[(k0 + i) * ASTRIDE + elem] = fmaxf(acc[i], 0.f);

    LOAD8(br2 + k0, acc);
#pragma unroll 2
    for (int j = 0; j < H; ++j) {
        float a = act[j * ASTRIDE + elem];
        FMA8(a, Wr2 + j * H + k0, acc);
    }

    float4* o4 = (float4*)(out + (size_t)eb * H + k0);
    o4[0] = make_float4(acc[0], acc[1], acc[2], acc[3]);
    o4[1] = make_float4(acc[4], acc[5], acc[6], acc[7]);
}

extern "C" void kernel_launch(void* const* d_in, const int* in_sizes, int n_in,
                              void* d_out, int out_size, void* d_ws, size_t ws_size,
                              hipStream_t stream)
{
    const int*   seqs  = (const int*)d_in[0];
    const int*   qtok  = (const int*)d_in[1];
    const float* embed = (const float*)d_in[2];
    const float* W1    = (const float*)d_in[3];
    const float* b1    = (const float*)d_in[4];
    const float* W2    = (const float*)d_in[5];
    const float* b2    = (const float*)d_in[6];
    const float* Ww    = (const float*)d_in[7];
    const float* bw    = (const float*)d_in[8];
    const float* We    = (const float*)d_in[9];
    const float* be    = (const float*)d_in[10];
    const float* Wr1   = (const float*)d_in[11];
    const float* br1   = (const float*)d_in[12];
    const float* Wr2   = (const float*)d_in[13];
    const float* br2   = (const float*)d_in[14];
    float* out = (float*)d_out;
    float* ws  = (float*)d_ws;

    hipLaunchKernelGGL(k_setup_tables, dim3((NV * H + 255) / 256), dim3(256), 0, stream,
                       embed, W1, b1, Wr1, br1, ws);
    hipLaunchKernelGGL(k_main, dim3(NB / EPB), dim3(256), 0, stream,
                       W1, W2, b2, Ww, bw, We, be, Wr1, Wr2, br2, qtok, seqs, ws, out);
}

// Round 5
// 2091.562 us; speedup vs baseline: 2.0277x; 1.0403x over previous
//
#include <hip/hip_runtime.h>

#define H       64
#define NSLOT   4
#define NSTEP   23          // SEQ_LEN - 1
#define NB      65536
#define NV      66          // VOCAB_SIZE + 2
#define SEQL    24
#define LPE     8           // lanes per element
#define EPB     32          // elements per 256-thread block
#define ASTRIDE 33          // act leading stride (33%32==1: cheap writes, broadcast reads)

// ---- workspace layout (float offsets) ----
#define OFF_EW1   0                         // embW1b  [NV][H] = embed@W1[:64] + b1
#define OFF_EWR1  (NV * H)                  // embWr1b [NV][H] = embed@Wr1[:64] + br1

__global__ __launch_bounds__(256) void k_setup_tables(
    const float* __restrict__ embed, const float* __restrict__ W1, const float* __restrict__ b1,
    const float* __restrict__ Wr1, const float* __restrict__ br1, float* __restrict__ ws)
{
    int idx = blockIdx.x * 256 + threadIdx.x;
    if (idx >= NV * H) return;
    int t = idx >> 6, k = idx & 63;
    float a1 = b1[k], a2 = br1[k];
    for (int j = 0; j < H; ++j) {
        float e = embed[t * H + j];
        a1 = fmaf(e, W1[j * H + k], a1);
        a2 = fmaf(e, Wr1[j * H + k], a2);
    }
    ws[OFF_EW1 + idx]  = a1;
    ws[OFF_EWR1 + idx] = a2;
}

// 8-wide FMA into ACC from a weight-row chunk (2x global_load_dwordx4, vmcnt path)
#define FMA8(a, wptr, ACC) do {                                             \
    const float4* _w = (const float4*)(wptr);                               \
    float4 _w0 = _w[0], _w1 = _w[1];                                        \
    ACC[0]=fmaf((a),_w0.x,ACC[0]); ACC[1]=fmaf((a),_w0.y,ACC[1]);          \
    ACC[2]=fmaf((a),_w0.z,ACC[2]); ACC[3]=fmaf((a),_w0.w,ACC[3]);          \
    ACC[4]=fmaf((a),_w1.x,ACC[4]); ACC[5]=fmaf((a),_w1.y,ACC[5]);          \
    ACC[6]=fmaf((a),_w1.z,ACC[6]); ACC[7]=fmaf((a),_w1.w,ACC[7]);          \
} while (0)

#define LOAD8(ptr, A) do {                                                  \
    const float4* _b = (const float4*)(ptr);                                \
    float4 _b0 = _b[0], _b1 = _b[1];                                        \
    A[0]=_b0.x; A[1]=_b0.y; A[2]=_b0.z; A[3]=_b0.w;                        \
    A[4]=_b1.x; A[5]=_b1.y; A[6]=_b1.z; A[7]=_b1.w;                        \
} while (0)

__global__ __launch_bounds__(256, 4) void k_main(
    const float* __restrict__ W1, const float* __restrict__ W2, const float* __restrict__ b2,
    const float* __restrict__ Ww, const float* __restrict__ bw,
    const float* __restrict__ We, const float* __restrict__ be,
    const float* __restrict__ Wr1, const float* __restrict__ Wr2, const float* __restrict__ br2,
    const int* __restrict__ qtok, const int* __restrict__ seqs,
    const float* __restrict__ ws, float* __restrict__ out)
{
    // act[k*33 + elem]: per-element activation column. Each element's 8 lanes live
    // in ONE wave -> lockstep program order, no barriers needed for act.
    __shared__ float act[H * ASTRIDE];
    __shared__ float sWe[H * NSLOT];       // We staged once (kills 64 VMEM dword/step)
    const int tid  = threadIdx.x;
    const int m    = tid & (LPE - 1);      // chunk id 0..7
    const int elem = tid >> 3;             // 0..31 within block
    const int eb   = blockIdx.x * EPB + elem;
    const int k0   = m * 8;
    const int slot = m & 3;                // evict-logit slot this lane computes

    if (tid < H * NSLOT) sWe[tid] = We[tid];
    __syncthreads();                       // sWe is cross-wave shared

    const float* embW1b  = ws + OFF_EW1;
    const float* embWr1b = ws + OFF_EWR1;

    // register-resident memory state: 4 slots x 8 floats per lane (32 VGPRs)
    float mem0[8], mem1[8], mem2[8], mem3[8], contrib[8];
#pragma unroll
    for (int i = 0; i < 8; ++i) {
        mem0[i] = 0.f; mem1[i] = 0.f; mem2[i] = 0.f; mem3[i] = 0.f; contrib[i] = 0.f;
    }

    const float bes = be[slot];
    int tok = seqs[eb * SEQL];

    float acc[8];

#pragma unroll 1
    for (int t = 0; t < NSTEP; ++t) {
        int tok_n = seqs[eb * SEQL + t + 1];   // t+1 <= 23 < SEQL

        // h1 = relu(embW1b[tok] + contrib) -> act
        {
            float h[8];
            LOAD8(embW1b + tok * H + k0, h);
#pragma unroll
            for (int i = 0; i < 8; ++i)
                act[(k0 + i) * ASTRIDE + elem] = fmaxf(h[i] + contrib[i], 0.f);
        }

        // h2 = relu(h1 @ W2 + b2)
        LOAD8(b2 + k0, acc);
#pragma unroll 4
        for (int j = 0; j < H; ++j) {
            float a = act[j * ASTRIDE + elem];
            FMA8(a, W2 + j * H + k0, acc);
        }
#pragma unroll
        for (int i = 0; i < 8; ++i)
            act[(k0 + i) * ASTRIDE + elem] = fmaxf(acc[i], 0.f);

        // write_vec chunk = h2 @ Ww + bw ; evict logit for slot (m&3)
        float lg = bes;
        LOAD8(bw + k0, acc);
#pragma unroll 4
        for (int j = 0; j < H; ++j) {
            float a = act[j * ASTRIDE + elem];
            FMA8(a, Ww + j * H + k0, acc);
            lg = fmaf(a, sWe[j * NSLOT + slot], lg);
        }

        // gather the element's 4 logits (lanes base..base+3 hold slots 0..3)
        int base = tid & ~(LPE - 1);
        float v0 = __shfl(lg, base + 0);
        float v1 = __shfl(lg, base + 1);
        float v2 = __shfl(lg, base + 2);
        float v3 = __shfl(lg, base + 3);
        int e = 0; float best = v0;                 // first-max wins = jnp.argmax
        if (v1 > best) { best = v1; e = 1; }
        if (v2 > best) { best = v2; e = 2; }
        if (v3 > best) { best = v3; e = 3; }

        // mem[e] <- write_vec ; delta = write_vec - mem_old[e] -> act
        bool e0 = (e == 0), e1 = (e == 1), e2 = (e == 2), e3 = (e == 3);
#pragma unroll
        for (int i = 0; i < 8; ++i) {
            float old = e0 ? mem0[i] : e1 ? mem1[i] : e2 ? mem2[i] : mem3[i];
            float w = acc[i];
            mem0[i] = e0 ? w : mem0[i];
            mem1[i] = e1 ? w : mem1[i];
            mem2[i] = e2 ? w : mem2[i];
            mem3[i] = e3 ? w : mem3[i];
            act[(k0 + i) * ASTRIDE + elem] = w - old;
        }

        // contrib += delta @ W1mem_e (e uniform across the element's lanes)
        const float* W1e = W1 + (H + e * H) * H + k0;
#pragma unroll 4
        for (int j = 0; j < H; ++j) {
            float d = act[j * ASTRIDE + elem];
            FMA8(d, W1e + j * H, contrib);
        }

        tok = tok_n;
    }

    // ---- read head ----
#pragma unroll
    for (int i = 0; i < 8; ++i)
        act[(k0 + i) * ASTRIDE + elem] = 0.25f * (mem0[i] + mem1[i] + mem2[i] + mem3[i]);

    int q = qtok[eb];
    LOAD8(embWr1b + q * H + k0, acc);
#pragma unroll 4
    for (int j = 0; j < H; ++j) {
        float a = act[j * ASTRIDE + elem];
        FMA8(a, Wr1 + (H + j) * H + k0, acc);
    }
#pragma unroll
    for (int i = 0; i < 8; ++i)
        act[(k0 + i) * ASTRIDE + elem] = fmaxf(acc[i], 0.f);

    LOAD8(br2 + k0, acc);
#pragma unroll 4
    for (int j = 0; j < H; ++j) {
        float a = act[j * ASTRIDE + elem];
        FMA8(a, Wr2 + j * H + k0, acc);
    }

    float4* o4 = (float4*)(out + (size_t)eb * H + k0);
    o4[0] = make_float4(acc[0], acc[1], acc[2], acc[3]);
    o4[1] = make_float4(acc[4], acc[5], acc[6], acc[7]);
}

extern "C" void kernel_launch(void* const* d_in, const int* in_sizes, int n_in,
                              void* d_out, int out_size, void* d_ws, size_t ws_size,
                              hipStream_t stream)
{
    const int*   seqs  = (const int*)d_in[0];
    const int*   qtok  = (const int*)d_in[1];
    const float* embed = (const float*)d_in[2];
    const float* W1    = (const float*)d_in[3];
    const float* b1    = (const float*)d_in[4];
    const float* W2    = (const float*)d_in[5];
    const float* b2    = (const float*)d_in[6];
    const float* Ww    = (const float*)d_in[7];
    const float* bw    = (const float*)d_in[8];
    const float* We    = (const float*)d_in[9];
    const float* be    = (const float*)d_in[10];
    const float* Wr1   = (const float*)d_in[11];
    const float* br1   = (const float*)d_in[12];
    const float* Wr2   = (const float*)d_in[13];
    const float* br2   = (const float*)d_in[14];
    float* out = (float*)d_out;
    float* ws  = (float*)d_ws;

    hipLaunchKernelGGL(k_setup_tables, dim3((NV * H + 255) / 256), dim3(256), 0, stream,
                       embed, W1, b1, Wr1, br1, ws);
    hipLaunchKernelGGL(k_main, dim3(NB / EPB), dim3(256), 0, stream,
                       W1, W2, b2, Ww, bw, We, be, Wr1, Wr2, br2, qtok, seqs, ws, out);
}

// Round 6
// 932.518 us; speedup vs baseline: 4.5479x; 2.2429x over previous
//
#include <hip/hip_runtime.h>

#define H       64
#define NSLOT   4
#define NSTEP   23          // SEQ_LEN - 1
#define NB      65536
#define NV      66          // VOCAB_SIZE + 2
#define SEQL    24
#define LPE     8           // lanes per element
#define GELEM   2           // elements per lane (register-blocking)
#define TPB     512         // threads per block (8 waves)
#define EPB     128         // elements per block = TPB/LPE*GELEM
#define ACTSTR  132         // act column stride
#define W1RSTR  68          // sW1m row stride (floats)
#define W1SSTR  (64 * W1RSTR + 8)   // slot stride: +8 shifts banks per slot

// ---- workspace layout (float offsets) ----
#define OFF_EW1   0                         // embW1b  [NV][H] = embed@W1[:64] + b1
#define OFF_EWR1  (NV * H)                  // embWr1b [NV][H] = embed@Wr1[:64] + br1

__global__ __launch_bounds__(256) void k_setup_tables(
    const float* __restrict__ embed, const float* __restrict__ W1, const float* __restrict__ b1,
    const float* __restrict__ Wr1, const float* __restrict__ br1, float* __restrict__ ws)
{
    int idx = blockIdx.x * 256 + threadIdx.x;
    if (idx >= NV * H) return;
    int t = idx >> 6, k = idx & 63;
    float a1 = b1[k], a2 = br1[k];
    for (int j = 0; j < H; ++j) {
        float e = embed[t * H + j];
        a1 = fmaf(e, W1[j * H + k], a1);
        a2 = fmaf(e, Wr1[j * H + k], a2);
    }
    ws[OFF_EW1 + idx]  = a1;
    ws[OFF_EWR1 + idx] = a2;
}

#define FMA8V(w0, w1, a, ACC) do {                                          \
    ACC[0]=fmaf((a),w0.x,ACC[0]); ACC[1]=fmaf((a),w0.y,ACC[1]);            \
    ACC[2]=fmaf((a),w0.z,ACC[2]); ACC[3]=fmaf((a),w0.w,ACC[3]);            \
    ACC[4]=fmaf((a),w1.x,ACC[4]); ACC[5]=fmaf((a),w1.y,ACC[5]);            \
    ACC[6]=fmaf((a),w1.z,ACC[6]); ACC[7]=fmaf((a),w1.w,ACC[7]);            \
} while (0)

#define LOAD8(ptr, A) do {                                                  \
    const float4* _b = (const float4*)(ptr);                                \
    float4 _b0 = _b[0], _b1 = _b[1];                                        \
    A[0]=_b0.x; A[1]=_b0.y; A[2]=_b0.z; A[3]=_b0.w;                        \
    A[4]=_b1.x; A[5]=_b1.y; A[6]=_b1.z; A[7]=_b1.w;                        \
} while (0)

__global__ __launch_bounds__(TPB, 2) void k_main(
    const float* __restrict__ W1, const float* __restrict__ W2, const float* __restrict__ b2,
    const float* __restrict__ Ww, const float* __restrict__ bw,
    const float* __restrict__ We, const float* __restrict__ be,
    const float* __restrict__ Wr1, const float* __restrict__ Wr2, const float* __restrict__ br2,
    const int* __restrict__ qtok, const int* __restrict__ seqs,
    const float* __restrict__ ws, float* __restrict__ out)
{
    // LDS: W1mem (slot-padded, lgkmcnt pipe) + act transpose + We. ~105 KB.
    __shared__ float sW1m[NSLOT * W1SSTR];   // [s][j][k] at s*W1SSTR + j*W1RSTR + k
    __shared__ float act[H * ACTSTR];        // [j][elem], group-private columns
    __shared__ float sWe[H * NSLOT];

    const int tid  = threadIdx.x;
    const int m    = tid & (LPE - 1);        // chunk id 0..7
    const int g    = tid >> 3;               // group 0..63 (8 lanes, within one wave)
    const int eA   = g;                      // element A column (0..63)
    const int eB   = g + 64;                 // element B column (64..127)
    const int gidA = blockIdx.x * EPB + eA;
    const int gidB = blockIdx.x * EPB + eB;
    const int k0   = m * 8;
    const int slot = m & 3;

    // ---- stage W1mem + We into LDS ----
    for (int i = tid; i < NSLOT * H * H; i += TPB) {
        int s = i >> 12, r = (i >> 6) & 63, k = i & 63;
        sW1m[s * W1SSTR + r * W1RSTR + k] = W1[(H + s * H + r) * H + k];
    }
    if (tid < H * NSLOT) sWe[tid] = We[tid];
    __syncthreads();

    const float* embW1b  = ws + OFF_EW1;
    const float* embWr1b = ws + OFF_EWR1;

    // register state: 2 elements x (4 slots x 8 + contrib 8)
    float mA0[8], mA1[8], mA2[8], mA3[8], cA[8];
    float mB0[8], mB1[8], mB2[8], mB3[8], cB[8];
#pragma unroll
    for (int i = 0; i < 8; ++i) {
        mA0[i]=0.f; mA1[i]=0.f; mA2[i]=0.f; mA3[i]=0.f; cA[i]=0.f;
        mB0[i]=0.f; mB1[i]=0.f; mB2[i]=0.f; mB3[i]=0.f; cB[i]=0.f;
    }

    float b2r[8], bwr[8];
    LOAD8(b2 + k0, b2r);
    LOAD8(bw + k0, bwr);
    const float bes = be[slot];

    int tokA = seqs[gidA * SEQL];
    int tokB = seqs[gidB * SEQL];

    float accA[8], accB[8];

#pragma unroll 1
    for (int t = 0; t < NSTEP; ++t) {
        int tokAn = seqs[gidA * SEQL + t + 1];
        int tokBn = seqs[gidB * SEQL + t + 1];

        // h1 = relu(embW1b[tok] + contrib) -> act
        {
            float hA[8], hB[8];
            LOAD8(embW1b + tokA * H + k0, hA);
            LOAD8(embW1b + tokB * H + k0, hB);
#pragma unroll
            for (int i = 0; i < 8; ++i) {
                act[(k0 + i) * ACTSTR + eA] = fmaxf(hA[i] + cA[i], 0.f);
                act[(k0 + i) * ACTSTR + eB] = fmaxf(hB[i] + cB[i], 0.f);
            }
        }

        // h2 = relu(h1 @ W2 + b2)   (W2 via VMEM, one load feeds both elements)
#pragma unroll
        for (int i = 0; i < 8; ++i) { accA[i] = b2r[i]; accB[i] = b2r[i]; }
#pragma unroll 4
        for (int j = 0; j < H; ++j) {
            const float4* w = (const float4*)(W2 + j * H + k0);
            float4 w0 = w[0], w1 = w[1];
            float a0 = act[j * ACTSTR + eA];
            float a1 = act[j * ACTSTR + eB];
            FMA8V(w0, w1, a0, accA);
            FMA8V(w0, w1, a1, accB);
        }
#pragma unroll
        for (int i = 0; i < 8; ++i) {
            act[(k0 + i) * ACTSTR + eA] = fmaxf(accA[i], 0.f);
            act[(k0 + i) * ACTSTR + eB] = fmaxf(accB[i], 0.f);
        }

        // write_vec = h2 @ Ww + bw ; evict logit for slot (m&3)
        float lgA = bes, lgB = bes;
#pragma unroll
        for (int i = 0; i < 8; ++i) { accA[i] = bwr[i]; accB[i] = bwr[i]; }
#pragma unroll 4
        for (int j = 0; j < H; ++j) {
            const float4* w = (const float4*)(Ww + j * H + k0);
            float4 w0 = w[0], w1 = w[1];
            float a0 = act[j * ACTSTR + eA];
            float a1 = act[j * ACTSTR + eB];
            FMA8V(w0, w1, a0, accA);
            FMA8V(w0, w1, a1, accB);
            float we = sWe[j * NSLOT + slot];
            lgA = fmaf(a0, we, lgA);
            lgB = fmaf(a1, we, lgB);
        }

        // argmax per element (lanes base..base+3 hold slots 0..3)
        int base = (tid & 63) & ~(LPE - 1);
        float vA0 = __shfl(lgA, base + 0), vA1 = __shfl(lgA, base + 1);
        float vA2 = __shfl(lgA, base + 2), vA3 = __shfl(lgA, base + 3);
        float vB0 = __shfl(lgB, base + 0), vB1 = __shfl(lgB, base + 1);
        float vB2 = __shfl(lgB, base + 2), vB3 = __shfl(lgB, base + 3);
        int eSA = 0; float bstA = vA0;
        if (vA1 > bstA) { bstA = vA1; eSA = 1; }
        if (vA2 > bstA) { bstA = vA2; eSA = 2; }
        if (vA3 > bstA) { bstA = vA3; eSA = 3; }
        int eSB = 0; float bstB = vB0;
        if (vB1 > bstB) { bstB = vB1; eSB = 1; }
        if (vB2 > bstB) { bstB = vB2; eSB = 2; }
        if (vB3 > bstB) { bstB = vB3; eSB = 3; }

        // mem[e] <- write_vec ; delta -> act
        {
            bool a0 = (eSA == 0), a1 = (eSA == 1), a2 = (eSA == 2), a3 = (eSA == 3);
            bool b0 = (eSB == 0), b1 = (eSB == 1), b2_ = (eSB == 2), b3 = (eSB == 3);
#pragma unroll
            for (int i = 0; i < 8; ++i) {
                float oldA = a0 ? mA0[i] : a1 ? mA1[i] : a2 ? mA2[i] : mA3[i];
                float oldB = b0 ? mB0[i] : b1 ? mB1[i] : b2_ ? mB2[i] : mB3[i];
                float wA = accA[i], wB = accB[i];
                mA0[i] = a0 ? wA : mA0[i];  mA1[i] = a1 ? wA : mA1[i];
                mA2[i] = a2 ? wA : mA2[i];  mA3[i] = a3 ? wA : mA3[i];
                mB0[i] = b0 ? wB : mB0[i];  mB1[i] = b1 ? wB : mB1[i];
                mB2[i] = b2_ ? wB : mB2[i]; mB3[i] = b3 ? wB : mB3[i];
                act[(k0 + i) * ACTSTR + eA] = wA - oldA;
                act[(k0 + i) * ACTSTR + eB] = wB - oldB;
            }
        }

        // contrib += delta @ W1mem_e  (W1m via LDS, e uniform within group)
        const float* WA = sW1m + eSA * W1SSTR + k0;
        const float* WB = sW1m + eSB * W1SSTR + k0;
#pragma unroll 4
        for (int j = 0; j < H; ++j) {
            const float4* wa = (const float4*)(WA + j * W1RSTR);
            const float4* wb = (const float4*)(WB + j * W1RSTR);
            float4 wa0 = wa[0], wa1 = wa[1];
            float4 wb0 = wb[0], wb1 = wb[1];
            float dA = act[j * ACTSTR + eA];
            float dB = act[j * ACTSTR + eB];
            FMA8V(wa0, wa1, dA, cA);
            FMA8V(wb0, wb1, dB, cB);
        }

        tokA = tokAn; tokB = tokBn;
    }

    // ---- read head ----
#pragma unroll
    for (int i = 0; i < 8; ++i) {
        act[(k0 + i) * ACTSTR + eA] = 0.25f * (mA0[i] + mA1[i] + mA2[i] + mA3[i]);
        act[(k0 + i) * ACTSTR + eB] = 0.25f * (mB0[i] + mB1[i] + mB2[i] + mB3[i]);
    }

    int qA = qtok[gidA], qB = qtok[gidB];
    LOAD8(embWr1b + qA * H + k0, accA);
    LOAD8(embWr1b + qB * H + k0, accB);
#pragma unroll 4
    for (int j = 0; j < H; ++j) {
        const float4* w = (const float4*)(Wr1 + (H + j) * H + k0);
        float4 w0 = w[0], w1 = w[1];
        float a0 = act[j * ACTSTR + eA];
        float a1 = act[j * ACTSTR + eB];
        FMA8V(w0, w1, a0, accA);
        FMA8V(w0, w1, a1, accB);
    }
#pragma unroll
    for (int i = 0; i < 8; ++i) {
        act[(k0 + i) * ACTSTR + eA] = fmaxf(accA[i], 0.f);
        act[(k0 + i) * ACTSTR + eB] = fmaxf(accB[i], 0.f);
    }

    LOAD8(br2 + k0, accA);
#pragma unroll
    for (int i = 0; i < 8; ++i) accB[i] = accA[i];
#pragma unroll 4
    for (int j = 0; j < H; ++j) {
        const float4* w = (const float4*)(Wr2 + j * H + k0);
        float4 w0 = w[0], w1 = w[1];
        float a0 = act[j * ACTSTR + eA];
        float a1 = act[j * ACTSTR + eB];
        FMA8V(w0, w1, a0, accA);
        FMA8V(w0, w1, a1, accB);
    }

    float4* oA = (float4*)(out + (size_t)gidA * H + k0);
    oA[0] = make_float4(accA[0], accA[1], accA[2], accA[3]);
    oA[1] = make_float4(accA[4], accA[5], accA[6], accA[7]);
    float4* oB = (float4*)(out + (size_t)gidB * H + k0);
    oB[0] = make_float4(accB[0], accB[1], accB[2], accB[3]);
    oB[1] = make_float4(accB[4], accB[5], accB[6], accB[7]);
}

extern "C" void kernel_launch(void* const* d_in, const int* in_sizes, int n_in,
                              void* d_out, int out_size, void* d_ws, size_t ws_size,
                              hipStream_t stream)
{
    const int*   seqs  = (const int*)d_in[0];
    const int*   qtok  = (const int*)d_in[1];
    const float* embed = (const float*)d_in[2];
    const float* W1    = (const float*)d_in[3];
    const float* b1    = (const float*)d_in[4];
    const float* W2    = (const float*)d_in[5];
    const float* b2    = (const float*)d_in[6];
    const float* Ww    = (const float*)d_in[7];
    const float* bw    = (const float*)d_in[8];
    const float* We    = (const float*)d_in[9];
    const float* be    = (const float*)d_in[10];
    const float* Wr1   = (const float*)d_in[11];
    const float* br1   = (const float*)d_in[12];
    const float* Wr2   = (const float*)d_in[13];
    const float* br2   = (const float*)d_in[14];
    float* out = (float*)d_out;
    float* ws  = (float*)d_ws;

    hipLaunchKernelGGL(k_setup_tables, dim3((NV * H + 255) / 256), dim3(256), 0, stream,
                       embed, W1, b1, Wr1, br1, ws);
    hipLaunchKernelGGL(k_main, dim3(NB / EPB), dim3(TPB), 0, stream,
                       W1, W2, b2, Ww, bw, We, be, Wr1, Wr2, br2, qtok, seqs, ws, out);
}